// Round 7
// baseline (138.337 us; speedup 1.0000x reference)
//
#include <hip/hip_runtime.h>

typedef unsigned short u16;
typedef unsigned int u32;
typedef __bf16 bf16x8 __attribute__((ext_vector_type(8)));
typedef float f32x16 __attribute__((ext_vector_type(16)));

#define C2 (-7.213475204444817f) /* -5/ln2 : exp(-5 t^2) = exp2(C2 t^2) */
#define T1C 0.28650480f          /* e^-1.25 */
#define T2C 0.0067379470f        /* e^-5    */

__device__ __forceinline__ u16 f2bf(float f) {
  u32 u = __float_as_uint(f);
  return (u16)((u + 0x7FFFu + ((u >> 16) & 1u)) >> 16);  // RNE
}

__device__ __forceinline__ f32x16 mfma16(uint4 a, uint4 b, f32x16 c) {
  return __builtin_amdgcn_mfma_f32_32x32x16_bf16(
      __builtin_bit_cast(bf16x8, a), __builtin_bit_cast(bf16x8, b), c, 0, 0, 0);
}

// ---------------------------------------------------------------------------
// Prep (unchanged; validated): f32 weights -> bf16, per-16k-chunk fragment
// order. wst3 granule(c, g) 16 B, g = s*256 + nq*64 + l:
//   content = W_s[k = c*16 + (l>>5)*8 + 0..8)[u = nq*32 + (l&31)]
// ---------------------------------------------------------------------------
__global__ __launch_bounds__(256) void kan_prep(const float* __restrict__ wb,
                                                const float* __restrict__ ws,
                                                u16* __restrict__ wst3) {
  __shared__ u16 tile[6][16][130];
  const int t = threadIdx.x;
  const int c = blockIdx.x;
#pragma unroll
  for (int it = 0; it < 8; ++it) {
    int idx = it * 256 + t;
    int d = idx >> 7, u = idx & 127;
    size_t base = (size_t)(c * 16 + d) * 128 + u;
    const float* p = ws + base * 8;
    float4 v0 = *(const float4*)p;
    float g4 = p[4];
    tile[0][d][u] = f2bf(v0.x);
    tile[1][d][u] = f2bf(v0.y);
    tile[2][d][u] = f2bf(v0.z);
    tile[3][d][u] = f2bf(v0.w);
    tile[4][d][u] = f2bf(g4);
    tile[5][d][u] = f2bf(wb[base]);
  }
  __syncthreads();
#pragma unroll
  for (int i = 0; i < 6; ++i) {
    int g = i * 256 + t;
    int s = g >> 8, r = g & 255;
    int nq = r >> 6, l = r & 63;
    int u = nq * 32 + (l & 31);
    int dbase = (l >> 5) * 8;
    u32 q[4];
#pragma unroll
    for (int j = 0; j < 4; ++j) {
      u32 lo = tile[s][dbase + 2 * j][u];
      u32 hi = tile[s][dbase + 2 * j + 1][u];
      q[j] = lo | (hi << 16);
    }
    uint4 w4; w4.x = q[0]; w4.y = q[1]; w4.z = q[2]; w4.w = q[3];
    *(uint4*)(wst3 + (size_t)c * 12288 + (size_t)g * 8) = w4;
  }
}

// ---------------------------------------------------------------------------
// Main R14: TWO independent blocks per CU (cross-block barrier overlap, the
// m97 mechanism).  M=32/block, 256 thr = 4 waves (kq = k-quarter), grid 512.
// LDS 2 x 24 KB dbuf = 48 KB/block -> 2 blocks/CU at 2 waves/SIMD
// (launch_bounds(256,2) = 256-VGPR budget; R9's spill cliff avoided).
// Each wave owns FULL N=128: acc sp[4]+ba[4] (8 x f32x16 = 128 AGPR);
// every A-granule read ONCE (4x less LDS-read than R11/R13) and acc is
// 4-interleaved (reuse distance 4 MFMAs = ~128 cyc > dep latency).
// Homogeneous waves: per body (BK=64) issue B slabs 0-2 (12 dwordx4, L2),
// rbf(next body) covers their latency, issue B slabs 3-5 (cover under
// slab 0-2 MFMAs), then 6 x {1 A ds_read_b128 + 4 MFMA}.  One barrier/body.
// Layouts (validated R2-R13, strides rescaled to M=32):
//   A granule (s, p=chunk, kh): byte s*4096 + p*1024 + kh*512 +
//     ((m^(p*2+kh))&31)*16; writer (r,o): s*4096 + (o>>1)*1024 + (o&1)*512
//     + ((r^o)&31)*16.  B: chunk c=i*4+kq: c*24576 + s*4096 + nt*1024 +
//     lane*16.  mfma A[m=lane&31][k=(lane>>5)*8+j]; C/D col=lane&31,
//     row=(reg&3)+8*(reg>>2)+4*(lane>>5).
// Epilogue: 4-way k-merge in 2 rounds of 4 accs (3 kq x 4 x 4 KB = 48 KB).
// ---------------------------------------------------------------------------
__global__ __launch_bounds__(256, 2) void kan_main(const float* __restrict__ x,
                                                   const u16* __restrict__ wst3,
                                                   float* __restrict__ out) {
  __shared__ __align__(16) char lds[49152];  // 2 x 24576

  const int t = threadIdx.x;
  const int lane = t & 63;
  const int kq = t >> 6;  // wave = k-quarter
  const int b0 = blockIdx.x * 32;

  // ---- rbf writer: thread owns row r, k-octet o of each BK=64 body
  const int r = t >> 3, o = t & 7;
  const u32 aw = ((u32)(o >> 1) << 10) + ((u32)(o & 1) << 9) +
                 ((u32)((r ^ o) & 31) << 4);
  const float* xp = x + (size_t)(b0 + r) * 1024 + o * 8;

  // ---- A reader: chunk p = kq
  const int m = lane & 31, kh = lane >> 5;
  const u32 ar = ((u32)kq << 10) + ((u32)kh << 9) +
                 ((u32)((m ^ (kq * 2 + kh)) & 31) << 4);

  // ---- B source: chunk c = i*4 + kq
  const char* bsrc = (const char*)wst3 + (size_t)kq * 24576 + lane * 16;

  f32x16 sp[4], ba[4];
#pragma unroll
  for (int i = 0; i < 4; ++i)
#pragma unroll
    for (int j = 0; j < 16; ++j) { sp[i][j] = 0.f; ba[i][j] = 0.f; }

  auto rbf_write = [&](char* buf, float4 xa, float4 xb) {
    float xf[8] = {xa.x, xa.y, xa.z, xa.w, xb.x, xb.y, xb.z, xb.w};
    u32 pk[6][4];
#pragma unroll
    for (int pp = 0; pp < 4; ++pp) {
      u32 lo6[6], hi6[6];
#pragma unroll
      for (int e = 0; e < 2; ++e) {
        float xv = xf[2 * pp + e];
        float t0 = C2 * xv;
        float P = __builtin_amdgcn_exp2f(t0 * xv);  // e^{-5x^2}
        float Qp = __builtin_amdgcn_exp2f(-t0);     // e^{+5x}
        float Qm = __builtin_amdgcn_exp2f(t0);      // e^{-5x}
        float PQ = P * Qp, PQm = P * Qm;
        u32* dst = e ? hi6 : lo6;
        dst[0] = __float_as_uint(PQm * Qm * T2C) + 0x8000u;
        dst[1] = __float_as_uint(PQm * T1C) + 0x8000u;
        dst[2] = __float_as_uint(P) + 0x8000u;
        dst[3] = __float_as_uint(PQ * T1C) + 0x8000u;
        dst[4] = __float_as_uint(PQ * Qp * T2C) + 0x8000u;
        dst[5] = __float_as_uint(xv) + 0x8000u;
      }
#pragma unroll
      for (int s = 0; s < 6; ++s)
        pk[s][pp] = __builtin_amdgcn_perm(hi6[s], lo6[s], 0x07060302);
    }
#pragma unroll
    for (int s = 0; s < 6; ++s) {
      uint4 v; v.x = pk[s][0]; v.y = pk[s][1]; v.z = pk[s][2]; v.w = pk[s][3];
      *(uint4*)(buf + s * 4096 + aw) = v;
    }
  };

  // ---- prologue: body 0 -> buf0; prefetch x for body 1
  float4 xc0 = *(const float4*)(xp);
  float4 xc1 = *(const float4*)(xp + 4);
  rbf_write(lds, xc0, xc1);
  xc0 = *(const float4*)(xp + 64);
  xc1 = *(const float4*)(xp + 68);
  __syncthreads();

  for (int i = 0; i < 16; ++i) {
    char* cur = lds + (i & 1) * 24576;
    char* nxt = lds + ((i + 1) & 1) * 24576;
    const char* bc = bsrc + (size_t)i * 98304;

    // B slabs 0-2 (latency covered by rbf below)
    uint4 bvA[3][4];
#pragma unroll
    for (int s = 0; s < 3; ++s)
#pragma unroll
      for (int nt = 0; nt < 4; ++nt)
        bvA[s][nt] = *(const uint4*)(bc + s * 4096 + nt * 1024);

    if (i < 15) {
      rbf_write(nxt, xc0, xc1);
      if (i < 14) {
        xc0 = *(const float4*)(xp + (i + 2) * 64);
        xc1 = *(const float4*)(xp + (i + 2) * 64 + 4);
      }
    }

    // B slabs 3-5 (latency covered by slab 0-2 MFMAs)
    uint4 bvB[3][4];
#pragma unroll
    for (int s = 0; s < 3; ++s)
#pragma unroll
      for (int nt = 0; nt < 4; ++nt)
        bvB[s][nt] = *(const uint4*)(bc + (s + 3) * 4096 + nt * 1024);

    __builtin_amdgcn_s_setprio(1);
#pragma unroll
    for (int s = 0; s < 3; ++s) {
      uint4 av = *(const uint4*)(cur + s * 4096 + ar);
#pragma unroll
      for (int nt = 0; nt < 4; ++nt) sp[nt] = mfma16(av, bvA[s][nt], sp[nt]);
    }
#pragma unroll
    for (int s = 0; s < 2; ++s) {
      uint4 av = *(const uint4*)(cur + (s + 3) * 4096 + ar);
#pragma unroll
      for (int nt = 0; nt < 4; ++nt) sp[nt] = mfma16(av, bvB[s][nt], sp[nt]);
    }
    {
      uint4 av = *(const uint4*)(cur + 5 * 4096 + ar);
#pragma unroll
      for (int nt = 0; nt < 4; ++nt) ba[nt] = mfma16(av, bvB[2][nt], ba[nt]);
    }
    __builtin_amdgcn_s_setprio(0);
    __syncthreads();
  }

  // ---- epilogue: 4-way k-merge, 2 rounds of 4 accs (3 kq x 16 KB = 48 KB)
#pragma unroll
  for (int rd = 0; rd < 2; ++rd) {
    if (kq != 0) {
      char* slab = lds + (kq - 1) * 16384;
#pragma unroll
      for (int rq = 0; rq < 4; ++rq) {
        *(float4*)(slab + 0 * 4096 + rq * 1024 + lane * 16) =
            make_float4(sp[2 * rd][4 * rq], sp[2 * rd][4 * rq + 1],
                        sp[2 * rd][4 * rq + 2], sp[2 * rd][4 * rq + 3]);
        *(float4*)(slab + 1 * 4096 + rq * 1024 + lane * 16) =
            make_float4(sp[2 * rd + 1][4 * rq], sp[2 * rd + 1][4 * rq + 1],
                        sp[2 * rd + 1][4 * rq + 2], sp[2 * rd + 1][4 * rq + 3]);
        *(float4*)(slab + 2 * 4096 + rq * 1024 + lane * 16) =
            make_float4(ba[2 * rd][4 * rq], ba[2 * rd][4 * rq + 1],
                        ba[2 * rd][4 * rq + 2], ba[2 * rd][4 * rq + 3]);
        *(float4*)(slab + 3 * 4096 + rq * 1024 + lane * 16) =
            make_float4(ba[2 * rd + 1][4 * rq], ba[2 * rd + 1][4 * rq + 1],
                        ba[2 * rd + 1][4 * rq + 2], ba[2 * rd + 1][4 * rq + 3]);
      }
    }
    __syncthreads();
    if (kq == 0) {
#pragma unroll
      for (int p = 1; p < 4; ++p) {
        const char* slab = lds + (p - 1) * 16384;
#pragma unroll
        for (int rq = 0; rq < 4; ++rq) {
          float4 v0 = *(const float4*)(slab + 0 * 4096 + rq * 1024 + lane * 16);
          float4 v1 = *(const float4*)(slab + 1 * 4096 + rq * 1024 + lane * 16);
          float4 v2 = *(const float4*)(slab + 2 * 4096 + rq * 1024 + lane * 16);
          float4 v3 = *(const float4*)(slab + 3 * 4096 + rq * 1024 + lane * 16);
          sp[2 * rd][4 * rq] += v0.x; sp[2 * rd][4 * rq + 1] += v0.y;
          sp[2 * rd][4 * rq + 2] += v0.z; sp[2 * rd][4 * rq + 3] += v0.w;
          sp[2 * rd + 1][4 * rq] += v1.x; sp[2 * rd + 1][4 * rq + 1] += v1.y;
          sp[2 * rd + 1][4 * rq + 2] += v1.z; sp[2 * rd + 1][4 * rq + 3] += v1.w;
          ba[2 * rd][4 * rq] += v2.x; ba[2 * rd][4 * rq + 1] += v2.y;
          ba[2 * rd][4 * rq + 2] += v2.z; ba[2 * rd][4 * rq + 3] += v2.w;
          ba[2 * rd + 1][4 * rq] += v3.x; ba[2 * rd + 1][4 * rq + 1] += v3.y;
          ba[2 * rd + 1][4 * rq + 2] += v3.z; ba[2 * rd + 1][4 * rq + 3] += v3.w;
        }
      }
#pragma unroll
      for (int nti = 0; nti < 2; ++nti) {
        const int nt = 2 * rd + nti;
        const int col = nt * 32 + (lane & 31);
#pragma unroll
        for (int reg = 0; reg < 16; ++reg) {
          int row = (reg & 3) + 8 * (reg >> 2) + 4 * (lane >> 5);
          float z = ba[nt][reg];
          float sv = z / (1.0f + __expf(-z));
          out[(size_t)(b0 + row) * 128 + col] = sv + sp[nt][reg];
        }
      }
    }
    __syncthreads();
  }
}

extern "C" void kernel_launch(void* const* d_in, const int* in_sizes, int n_in,
                              void* d_out, int out_size, void* d_ws, size_t ws_size,
                              hipStream_t stream) {
  const float* x  = (const float*)d_in[0];   // [16384][1024] f32
  const float* wb = (const float*)d_in[1];   // [1024][128]   f32
  const float* ws = (const float*)d_in[2];   // [1024][128][8] f32
  u16* wst3 = (u16*)d_ws;                    // [64][1536] granules, 1.5 MB
  float* out = (float*)d_out;                // [16384][128]  f32

  kan_prep<<<dim3(64), 256, 0, stream>>>(wb, ws, wst3);
  kan_main<<<dim3(512), 256, 0, stream>>>(x, wst3, out);
}